// Round 2
// baseline (274.543 us; speedup 1.0000x reference)
//
#include <hip/hip_runtime.h>
#include <stdint.h>

// Problem constants
#define T_TOK 1024
#define DIN   2048
#define NOUT  8192   // 2*O
#define OSL   4096   // O per slice
#define ROWS_PAD 1408
#define BM 128
#define BN 128
#define BK 32
#define NT (DIN / BK)   // 64 K-steps
#define BUF1 16384      // second LDS buffer base

typedef _Float16 f16x8 __attribute__((ext_vector_type(8)));
typedef _Float16 f16x2 __attribute__((ext_vector_type(2)));
typedef float    f32x4 __attribute__((ext_vector_type(4)));

__device__ __forceinline__ void gload16(const void* gp, void* lp) {
  __builtin_amdgcn_global_load_lds(
      (__attribute__((address_space(1))) void*)gp,
      (__attribute__((address_space(3))) void*)lp, 16, 0, 0);
}

__device__ __forceinline__ f16x2 u2h(uint32_t u) {
  union { uint32_t u; f16x2 h; } c; c.u = u; return c.h;
}

__device__ __forceinline__ f16x8 cvt_interleave(float4 f0, float4 f1) {
  // k-order [0,4,1,5,2,6,3,7] so packed-nibble pairs (n_j, n_{j+4}) line up
  f16x8 h;
  h[0] = (_Float16)f0.x; h[1] = (_Float16)f1.x;
  h[2] = (_Float16)f0.y; h[3] = (_Float16)f1.y;
  h[4] = (_Float16)f0.z; h[5] = (_Float16)f1.z;
  h[6] = (_Float16)f0.w; h[7] = (_Float16)f1.w;
  return h;
}

#define VMCNT5() asm volatile("s_waitcnt vmcnt(5)" ::: "memory")
#define VMCNT0() asm volatile("s_waitcnt vmcnt(0)" ::: "memory")
#define LGKM0()  asm volatile("s_waitcnt lgkmcnt(0)" ::: "memory")
#define SB0()    __builtin_amdgcn_sched_barrier(0)

// ============ prep: sort + x->fp16 only (no weight materialization at all) ============
// blocks: [0] sort | [1, 1+T_TOK] x rows (last = zero pad row)
__global__ void prep(const float* __restrict__ x, const int* __restrict__ indices,
                     _Float16* __restrict__ xh, int* __restrict__ inv,
                     int* __restrict__ meta)
{
  const int b = blockIdx.x;
  const int tid = threadIdx.x;

  if (b == 0) {  // ---- token sort into 128-aligned adapter groups ----
    __shared__ int cnt[4], cur[4];
    if (tid < 4) cnt[tid] = 0;
    __syncthreads();
    for (int t = tid; t < T_TOK; t += 256) atomicAdd(&cnt[indices[t]], 1);
    __syncthreads();
    if (tid == 0) {
      int off = 0;
      for (int a = 0; a < 4; ++a) {
        meta[a] = off;
        meta[5 + a] = off + cnt[a];
        cur[a] = off;
        off = (off + cnt[a] + 127) & ~127;
      }
      meta[4] = off;
    }
    __syncthreads();
    for (int i = tid; i < ROWS_PAD; i += 256) inv[i] = -1;
    __syncthreads();
    for (int t = tid; t < T_TOK; t += 256) {
      int a = indices[t];
      int p = atomicAdd(&cur[a], 1);
      inv[p] = t;
    }
    return;
  }

  // ---- x -> fp16, interleaved ----
  const int row = b - 1;          // 0..T_TOK (T_TOK = zero row)
  const int d0 = tid * 8;
  f16x8 h;
  if (row < T_TOK) {
    const float* src = x + (size_t)row * DIN + d0;
    h = cvt_interleave(*(const float4*)src, *(const float4*)(src + 4));
  } else {
#pragma unroll
    for (int j = 0; j < 8; ++j) h[j] = (_Float16)0.0f;
  }
  *(f16x8*)(xh + (size_t)row * DIN + d0) = h;
}

// ============ fused GEMM: wb f32->f16 + 4-bit dequant in-loop, minimum 2-phase ======
// 128x128 tile, BK=32, 4 waves (2x2 of 64x64), 16x16x32 f16 MFMA.
// One s_barrier per K-tile. A staged via global_load_lds (XOR chunk swizzle);
// B built in regs (f32 wb + nibbles) -> ds_write. Counted vmcnt(5) before barrier
// (the 5 register loads for tile t+2 stay in flight across it).
__global__ __launch_bounds__(256) void kfuse(
    const _Float16* __restrict__ xh, const float* __restrict__ wbf32,
    const int* __restrict__ qw0, const int* __restrict__ qw1,
    const int* __restrict__ qz0, const int* __restrict__ qz1,
    const float* __restrict__ sc0, const float* __restrict__ sc1,
    const float* __restrict__ bias,
    const int* __restrict__ inv, const int* __restrict__ meta,
    float* __restrict__ out)
{
  // XCD-bijective swizzle (704 = 8*88): xcd = id%8 owns n-tiles [xcd*8, xcd*8+8)
  // across ALL m-tiles -> its wb/qw slice stays L2-resident for the m-sweep.
  const int id = blockIdx.y * 64 + blockIdx.x;            // dispatch-linear, 0..703
  const int m0 = (id >> 6) * BM;
  const int n0 = (((id & 7) << 3) | ((id >> 3) & 7)) * BN;

  if (m0 >= meta[4]) return;
  int ad = 0;
  if (m0 >= meta[1]) ad = 1;
  if (m0 >= meta[2]) ad = 2;
  if (m0 >= meta[3]) ad = 3;
  if (m0 >= meta[5 + ad]) return;      // tile entirely pad

  const int sl = n0 >> 12;
  const int tid  = threadIdx.x;
  const int wave = tid >> 6;
  const int lane = tid & 63;
  const int quad = lane >> 4;
  const int l16  = lane & 15;
  const int wm = (wave & 1) << 6;
  const int wn = (wave >> 1) << 6;

  __shared__ __align__(16) char smem[32768];  // buf0 [0,16K), buf1 [16K,32K); per buf: A[0,8K) B[8K,16K)

  f32x4 acc[4][4];
#pragma unroll
  for (int i = 0; i < 4; ++i)
#pragma unroll
    for (int j = 0; j < 4; ++j) acc[i][j] = (f32x4)0.0f;

  // A staging: staged chunk (tid&3) holds source chunk (tid&3)^((row>>1)&3)
  const int kch = (((tid & 3) ^ ((tid >> 3) & 3)) << 3);
  const int rloc = tid >> 2;
  int r0 = inv[m0 + rloc];       if (r0 < 0) r0 = T_TOK;   // pad -> zero row
  int r1 = inv[m0 + rloc + 64];  if (r1 < 0) r1 = T_TOK;
  const _Float16* ag0 = xh + (size_t)r0 * DIN + kch;
  const _Float16* ag1 = xh + (size_t)r1 * DIN + kch;
  const int saoff0 = wave * 1024;
  const int saoff1 = 4096 + wave * 1024;

  // B dequant setup: thread -> row o_local, k-half (tid&1)
  const int o_local = tid >> 1;
  const int o = n0 + o_local;
  const int o_sl = o & (OSL - 1);
  const int* qwp = (sl ? qw1 : qw0) + ((size_t)ad * OSL + o_sl) * (DIN / 8) + ((tid & 1) << 1);
  const int zw = (sl ? qz1 : qz0)[ad * (OSL / 8) + (o_sl >> 3)];
  const float s = (sl ? sc1 : sc0)[(size_t)ad * OSL + o_sl];
  const int z = (zw >> ((o_sl & 7) << 2)) & 0xF;
  f16x2 s2; s2[0] = s2[1] = (_Float16)s;
  f16x2 k2; k2[0] = k2[1] = (_Float16)(float)(-(1024 + z));
  const float* wbp = wbf32 + (size_t)o * DIN + ((tid & 1) << 4);  // f32 base rows

  const int bswz = (o_local >> 1) & 3;
  const int bwoff0 = 8192 + o_local * 64 + (((((tid & 1) << 1)    ) ^ bswz) << 4);
  const int bwoff1 = 8192 + o_local * 64 + (((((tid & 1) << 1) | 1) ^ bswz) << 4);
  const int qoff = ((quad ^ ((l16 >> 1) & 3)) << 4);

  auto LOADREGS = [&](int t, int2& qv, float4* f) {
    qv   = *(const int2*)(qwp + t * 4);
    f[0] = *(const float4*)(wbp + t * BK);
    f[1] = *(const float4*)(wbp + t * BK + 4);
    f[2] = *(const float4*)(wbp + t * BK + 8);
    f[3] = *(const float4*)(wbp + t * BK + 12);
  };
  auto DEQW = [&](int bb, int2 qv, const float4* f) {
    union U { f16x8 v; f16x2 p[4]; } A_, B_, h0, h1;
    A_.v = cvt_interleave(f[0], f[1]);   // cols base..base+7   (interleaved)
    B_.v = cvt_interleave(f[2], f[3]);   // cols base+8..base+15
    const uint32_t wx = (uint32_t)qv.x, wy = (uint32_t)qv.y;
#pragma unroll
    for (int j = 0; j < 4; ++j) {
      uint32_t t0 = ((wx >> (4 * j)) & 0x000F000Fu) | 0x64006400u;
      uint32_t t1 = ((wy >> (4 * j)) & 0x000F000Fu) | 0x64006400u;
      h0.p[j] = (u2h(t0) + k2) * s2 + A_.p[j];
      h1.p[j] = (u2h(t1) + k2) * s2 + B_.p[j];
    }
    *(f16x8*)(smem + bb + bwoff0) = h0.v;
    *(f16x8*)(smem + bb + bwoff1) = h1.v;
  };
  auto COMPUTE = [&](int bb) {
    f16x8 af[4], bf[4];
#pragma unroll
    for (int t = 0; t < 4; ++t)
      af[t] = *(const f16x8*)(smem + bb + (wm + t * 16 + l16) * 64 + qoff);
#pragma unroll
    for (int t = 0; t < 4; ++t)
      bf[t] = *(const f16x8*)(smem + bb + 8192 + (wn + t * 16 + l16) * 64 + qoff);
    __builtin_amdgcn_s_setprio(1);
#pragma unroll
    for (int mt = 0; mt < 4; ++mt)
#pragma unroll
      for (int nt = 0; nt < 4; ++nt)
        acc[mt][nt] = __builtin_amdgcn_mfma_f32_16x16x32_f16(af[mt], bf[nt], acc[mt][nt], 0, 0, 0);
    __builtin_amdgcn_s_setprio(0);
  };

  int2 qvA, qvB;
  float4 fA[4], fB[4];

  // ---- prologue: make buf0 = tile 0; load regs(1) ----
  LOADREGS(0, qvB, fB);
  gload16(ag0, smem + saoff0);
  gload16(ag1, smem + saoff1);
  VMCNT0(); SB0();                 // A(0) landed, regs(0) ready
  DEQW(0, qvB, fB);                // B(0) -> buf0
  LOADREGS(1, qvA, fA);            // regs(1), in flight across barrier
  LGKM0();                         // ds_writes drained
  __builtin_amdgcn_s_barrier(); SB0();

  // iter t (even: cur=buf0, P=A holds regs(t+1), N=B gets regs(t+2)):
  //   STAGE A(t+1)->buf^1 | LOADREGS(t+2)->N | COMPUTE(cur) | DEQW(buf^1, P=regs(t+1))
  //   vmcnt(5): A(t+1) landed, regs(t+2) stay in flight | lgkm(0) | barrier
  auto ITER_FULL = [&](int bb_cur, int bb_nxt, int t, int2& qvP, float4* fP,
                       int2& qvN, float4* fN) {
    gload16(ag0 + (t + 1) * BK, smem + bb_nxt + saoff0);
    gload16(ag1 + (t + 1) * BK, smem + bb_nxt + saoff1);
    SB0();                                  // pin: stage issued before reg loads
    LOADREGS(t + 2, qvN, fN);
    COMPUTE(bb_cur);                        // compiler inserts lgkm waits for frags
    DEQW(bb_nxt, qvP, fP);                  // compiler inserts vmcnt wait for regs(t+1)
    SB0(); VMCNT5(); SB0();                 // 5 newest = regs(t+2); stage(t+1) drained
    LGKM0();                                // B(t+1) ds_writes visible
    __builtin_amdgcn_s_barrier(); SB0();
  };

  for (int t = 0; t < NT - 4; t += 2) {     // iters 0..59
    ITER_FULL(0, BUF1, t,     qvA, fA, qvB, fB);
    ITER_FULL(BUF1, 0, t + 1, qvB, fB, qvA, fA);
  }
  // iters 60, 61 (still full)
  ITER_FULL(0, BUF1, NT - 4, qvA, fA, qvB, fB);      // LOADREGS(62)->B, DEQW(61)
  ITER_FULL(BUF1, 0, NT - 3, qvB, fB, qvA, fA);      // LOADREGS(63)->A, DEQW(62)
  // iter 62: stage A(63), no more reg loads, DEQW(63), full drain
  gload16(ag0 + (NT - 1) * BK, smem + BUF1 + saoff0);
  gload16(ag1 + (NT - 1) * BK, smem + BUF1 + saoff1);
  COMPUTE(0);
  DEQW(BUF1, qvA, fA);                               // B(63) -> buf1
  SB0(); VMCNT0(); SB0(); LGKM0();
  __builtin_amdgcn_s_barrier(); SB0();
  // iter 63: compute only
  COMPUTE(BUF1);

  // C/D: col=lane&15, row=quad*4+reg; scatter to out[token], +bias
#pragma unroll
  for (int mt = 0; mt < 4; ++mt) {
    const int rowb = m0 + wm + mt * 16 + quad * 4;
    int tk[4];
#pragma unroll
    for (int r = 0; r < 4; ++r) tk[r] = inv[rowb + r];
#pragma unroll
    for (int nt = 0; nt < 4; ++nt) {
      const int col = n0 + wn + nt * 16 + l16;
      const float bv = bias[col];
#pragma unroll
      for (int r = 0; r < 4; ++r) {
        if (tk[r] >= 0)
          out[(size_t)tk[r] * NOUT + col] = acc[mt][nt][r] + bv;
      }
    }
  }
}

extern "C" void kernel_launch(void* const* d_in, const int* in_sizes, int n_in,
                              void* d_out, int out_size, void* d_ws, size_t ws_size,
                              hipStream_t stream) {
  const float* x    = (const float*)d_in[0];
  const float* wb   = (const float*)d_in[1];
  const float* bias = (const float*)d_in[2];
  const int*   qw0  = (const int*)d_in[3];
  const int*   qw1  = (const int*)d_in[4];
  const int*   qz0  = (const int*)d_in[5];
  const int*   qz1  = (const int*)d_in[6];
  const float* sc0  = (const float*)d_in[7];
  const float* sc1  = (const float*)d_in[8];
  const int*   indices = (const int*)d_in[11];
  float* out = (float*)d_out;

  // workspace: xh [(T_TOK+1)*DIN f16] | inv | meta  (~4.3 MB total)
  char* w = (char*)d_ws;
  _Float16* xh = (_Float16*)w;
  size_t off = (size_t)(T_TOK + 1) * DIN * 2;
  int* inv  = (int*)(w + off);
  int* meta = inv + ROWS_PAD;

  prep<<<2 + T_TOK, 256, 0, stream>>>(x, indices, xh, inv, meta);
  kfuse<<<dim3(64, 11), 256, 0, stream>>>(xh, wb, qw0, qw1, qz0, qz1, sc0, sc1,
                                          bias, inv, meta, out);
}

// Round 3
// 246.760 us; speedup vs baseline: 1.1126x; 1.1126x over previous
//
#include <hip/hip_runtime.h>
#include <stdint.h>

// Problem constants
#define T_TOK 1024
#define DIN   2048
#define NOUT  8192   // 2*O
#define OSL   4096   // O per slice
#define ROWS_PAD 1408
#define BM 128
#define BN 128
#define BK 32

typedef _Float16 f16x8 __attribute__((ext_vector_type(8)));
typedef _Float16 f16x2 __attribute__((ext_vector_type(2)));
typedef float    f32x4 __attribute__((ext_vector_type(4)));

__device__ __forceinline__ void gload16(const void* gp, void* lp) {
  __builtin_amdgcn_global_load_lds(
      (__attribute__((address_space(1))) void*)gp,
      (__attribute__((address_space(3))) void*)lp, 16, 0, 0);
}

__device__ __forceinline__ f16x2 u2h(uint32_t u) {
  union { uint32_t u; f16x2 h; } c; c.u = u; return c.h;
}

__device__ __forceinline__ f16x8 cvt_interleave(float4 f0, float4 f1) {
  // k-order [0,4,1,5,2,6,3,7] so packed-nibble pairs (n_j, n_{j+4}) line up
  f16x8 h;
  h[0] = (_Float16)f0.x; h[1] = (_Float16)f1.x;
  h[2] = (_Float16)f0.y; h[3] = (_Float16)f1.y;
  h[4] = (_Float16)f0.z; h[5] = (_Float16)f1.z;
  h[6] = (_Float16)f0.w; h[7] = (_Float16)f1.w;
  return h;
}

// ============ prep: sort + x->fp16 only (no weight materialization) ============
// blocks: [0] sort | [1, 1+T_TOK] x rows (last = zero pad row)
__global__ void prep(const float* __restrict__ x, const int* __restrict__ indices,
                     _Float16* __restrict__ xh, int* __restrict__ inv,
                     int* __restrict__ meta)
{
  const int b = blockIdx.x;
  const int tid = threadIdx.x;

  if (b == 0) {  // ---- token sort into 128-aligned adapter groups ----
    __shared__ int cnt[4], cur[4];
    if (tid < 4) cnt[tid] = 0;
    __syncthreads();
    for (int t = tid; t < T_TOK; t += 256) atomicAdd(&cnt[indices[t]], 1);
    __syncthreads();
    if (tid == 0) {
      int off = 0;
      for (int a = 0; a < 4; ++a) {
        meta[a] = off;
        meta[5 + a] = off + cnt[a];
        cur[a] = off;
        off = (off + cnt[a] + 127) & ~127;
      }
      meta[4] = off;
    }
    __syncthreads();
    for (int i = tid; i < ROWS_PAD; i += 256) inv[i] = -1;
    __syncthreads();
    for (int t = tid; t < T_TOK; t += 256) {
      int a = indices[t];
      int p = atomicAdd(&cur[a], 1);
      inv[p] = t;
    }
    return;
  }

  // ---- x -> fp16, interleaved ----
  const int row = b - 1;          // 0..T_TOK (T_TOK = zero row)
  const int d0 = tid * 8;
  f16x8 h;
  if (row < T_TOK) {
    const float* src = x + (size_t)row * DIN + d0;
    h = cvt_interleave(*(const float4*)src, *(const float4*)(src + 4));
  } else {
#pragma unroll
    for (int j = 0; j < 8; ++j) h[j] = (_Float16)0.0f;
  }
  *(f16x8*)(xh + (size_t)row * DIN + d0) = h;
}

// ============ fused GEMM: in-loop dequant from f32 wb + 4-bit qw ============
// R0-kslim loop structure VERBATIM (2x __syncthreads per K-step, single LDS
// buffer, compiler-scheduled waits, no inline asm, no sched_barriers, no
// setprio). Only the B-path differs from the proven 68us kernel: B is built
// in regs (f32 base row + nibbles -> f16) and ds_written, instead of read
// prebuilt. Dequant math identical to R1/R2 (verified passing).
__global__ __launch_bounds__(256) void kfuse(
    const _Float16* __restrict__ xh, const float* __restrict__ wbf32,
    const int* __restrict__ qw0, const int* __restrict__ qw1,
    const int* __restrict__ qz0, const int* __restrict__ qz1,
    const float* __restrict__ sc0, const float* __restrict__ sc1,
    const float* __restrict__ bias,
    const int* __restrict__ inv, const int* __restrict__ meta,
    float* __restrict__ out)
{
  // XCD-bijective swizzle (704 = 8*88): xcd = id%8 owns n-tiles [xcd*8, xcd*8+8)
  const int id = blockIdx.y * 64 + blockIdx.x;            // dispatch-linear, 0..703
  const int m0 = (id >> 6) * BM;
  const int n0 = (((id & 7) << 3) | ((id >> 3) & 7)) * BN;

  if (m0 >= meta[4]) return;
  int ad = 0;
  if (m0 >= meta[1]) ad = 1;
  if (m0 >= meta[2]) ad = 2;
  if (m0 >= meta[3]) ad = 3;
  if (m0 >= meta[5 + ad]) return;      // tile entirely pad

  const int sl = n0 >> 12;
  const int tid  = threadIdx.x;
  const int wave = tid >> 6;
  const int lane = tid & 63;
  const int quad = lane >> 4;
  const int l16  = lane & 15;
  const int wm = (wave & 1) << 6;
  const int wn = (wave >> 1) << 6;

  __shared__ __align__(16) char smem[16384];  // A [0,8K), B [8K,16K)

  f32x4 acc[4][4];
#pragma unroll
  for (int i = 0; i < 4; ++i)
#pragma unroll
    for (int j = 0; j < 4; ++j) acc[i][j] = (f32x4)0.0f;

  // A staging: staged chunk (tid&3) holds source chunk (tid&3)^((row>>1)&3)
  const int kch = (((tid & 3) ^ ((tid >> 3) & 3)) << 3);
  const int rloc = tid >> 2;
  int r0 = inv[m0 + rloc];       if (r0 < 0) r0 = T_TOK;   // pad -> zero row
  int r1 = inv[m0 + rloc + 64];  if (r1 < 0) r1 = T_TOK;
  const _Float16* ag0 = xh + (size_t)r0 * DIN + kch;
  const _Float16* ag1 = xh + (size_t)r1 * DIN + kch;
  char* sa0 = smem +        wave * 1024;
  char* sa1 = smem + 4096 + wave * 1024;

  // B dequant setup: thread -> row o_local, k-half (tid&1)
  const int o_local = tid >> 1;
  const int o = n0 + o_local;
  const int o_sl = o & (OSL - 1);
  const int* qwp = (sl ? qw1 : qw0) + ((size_t)ad * OSL + o_sl) * (DIN / 8) + ((tid & 1) << 1);
  const int zw = (sl ? qz1 : qz0)[ad * (OSL / 8) + (o_sl >> 3)];
  const float s = (sl ? sc1 : sc0)[(size_t)ad * OSL + o_sl];
  const int z = (zw >> ((o_sl & 7) << 2)) & 0xF;
  f16x2 s2; s2[0] = s2[1] = (_Float16)s;
  f16x2 k2; k2[0] = k2[1] = (_Float16)(float)(-(1024 + z));
  const float* wbp = wbf32 + (size_t)o * DIN + ((tid & 1) << 4);  // f32 base row

  const int bswz = (o_local >> 1) & 3;
  char* bw0 = smem + 8192 + o_local * 64 + (((((tid & 1) << 1)    ) ^ bswz) << 4);
  char* bw1 = smem + 8192 + o_local * 64 + (((((tid & 1) << 1) | 1) ^ bswz) << 4);
  const int qoff = ((quad ^ ((l16 >> 1) & 3)) << 4);

  for (int k0 = 0; k0 < DIN; k0 += BK) {
    gload16(ag0, sa0);
    gload16(ag1, sa1);
    const int2 qv = *(const int2*)qwp;
    const float4 f0 = *(const float4*)(wbp);
    const float4 f1 = *(const float4*)(wbp + 4);
    const float4 f2 = *(const float4*)(wbp + 8);
    const float4 f3 = *(const float4*)(wbp + 12);
    union U { f16x8 v; f16x2 p[4]; } A_, B_, h0, h1;
    A_.v = cvt_interleave(f0, f1);   // cols base..base+7   (interleaved)
    B_.v = cvt_interleave(f2, f3);   // cols base+8..base+15
    const uint32_t wx = (uint32_t)qv.x, wy = (uint32_t)qv.y;
#pragma unroll
    for (int j = 0; j < 4; ++j) {
      uint32_t t0 = ((wx >> (4 * j)) & 0x000F000Fu) | 0x64006400u;
      uint32_t t1 = ((wy >> (4 * j)) & 0x000F000Fu) | 0x64006400u;
      h0.p[j] = (u2h(t0) + k2) * s2 + A_.p[j];
      h1.p[j] = (u2h(t1) + k2) * s2 + B_.p[j];
    }
    *(f16x8*)bw0 = h0.v;
    *(f16x8*)bw1 = h1.v;
    __syncthreads();

    f16x8 af[4], bfr[4];
#pragma unroll
    for (int t = 0; t < 4; ++t)
      af[t] = *(const f16x8*)(smem + (wm + t * 16 + l16) * 64 + qoff);
#pragma unroll
    for (int t = 0; t < 4; ++t)
      bfr[t] = *(const f16x8*)(smem + 8192 + (wn + t * 16 + l16) * 64 + qoff);
#pragma unroll
    for (int mt = 0; mt < 4; ++mt)
#pragma unroll
      for (int nt = 0; nt < 4; ++nt)
        acc[mt][nt] = __builtin_amdgcn_mfma_f32_16x16x32_f16(af[mt], bfr[nt], acc[mt][nt], 0, 0, 0);
    __syncthreads();

    ag0 += BK; ag1 += BK; qwp += 4; wbp += BK;
  }

  // C/D: col=lane&15, row=quad*4+reg; scatter to out[token], +bias
#pragma unroll
  for (int mt = 0; mt < 4; ++mt) {
    const int rowb = m0 + wm + mt * 16 + quad * 4;
    int tk[4];
#pragma unroll
    for (int r = 0; r < 4; ++r) tk[r] = inv[rowb + r];
#pragma unroll
    for (int nt = 0; nt < 4; ++nt) {
      const int col = n0 + wn + nt * 16 + l16;
      const float bv = bias[col];
#pragma unroll
      for (int r = 0; r < 4; ++r) {
        if (tk[r] >= 0)
          out[(size_t)tk[r] * NOUT + col] = acc[mt][nt][r] + bv;
      }
    }
  }
}

extern "C" void kernel_launch(void* const* d_in, const int* in_sizes, int n_in,
                              void* d_out, int out_size, void* d_ws, size_t ws_size,
                              hipStream_t stream) {
  const float* x    = (const float*)d_in[0];
  const float* wb   = (const float*)d_in[1];
  const float* bias = (const float*)d_in[2];
  const int*   qw0  = (const int*)d_in[3];
  const int*   qw1  = (const int*)d_in[4];
  const int*   qz0  = (const int*)d_in[5];
  const int*   qz1  = (const int*)d_in[6];
  const float* sc0  = (const float*)d_in[7];
  const float* sc1  = (const float*)d_in[8];
  const int*   indices = (const int*)d_in[11];
  float* out = (float*)d_out;

  // workspace: xh [(T_TOK+1)*DIN f16] | inv | meta  (~4.3 MB total)
  char* w = (char*)d_ws;
  _Float16* xh = (_Float16*)w;
  size_t off = (size_t)(T_TOK + 1) * DIN * 2;
  int* inv  = (int*)(w + off);
  int* meta = inv + ROWS_PAD;

  prep<<<2 + T_TOK, 256, 0, stream>>>(x, indices, xh, inv, meta);
  kfuse<<<dim3(64, 11), 256, 0, stream>>>(xh, wb, qw0, qw1, qz0, qz1, sc0, sc1,
                                          bias, inv, meta, out);
}

// Round 7
// 245.715 us; speedup vs baseline: 1.1173x; 1.0043x over previous
//
#include <hip/hip_runtime.h>
#include <stdint.h>

// Problem constants
#define T_TOK 1024
#define DIN   2048
#define NOUT  8192   // 2*O
#define OSL   4096   // O per slice
#define ROWS_PAD 1408
#define BM 128
#define BN 64
#define BK 32

typedef _Float16 f16x8 __attribute__((ext_vector_type(8)));
typedef _Float16 f16x2 __attribute__((ext_vector_type(2)));
typedef float    f32x4 __attribute__((ext_vector_type(4)));

__device__ __forceinline__ void gload16(const void* gp, void* lp) {
  __builtin_amdgcn_global_load_lds(
      (__attribute__((address_space(1))) void*)gp,
      (__attribute__((address_space(3))) void*)lp, 16, 0, 0);
}

__device__ __forceinline__ f16x2 u2h(uint32_t u) {
  union { uint32_t u; f16x2 h; } c; c.u = u; return c.h;
}

__device__ __forceinline__ f16x8 cvt_interleave(float4 f0, float4 f1) {
  // k-order [0,4,1,5,2,6,3,7] so packed-nibble pairs (n_j, n_{j+4}) line up
  f16x8 h;
  h[0] = (_Float16)f0.x; h[1] = (_Float16)f1.x;
  h[2] = (_Float16)f0.y; h[3] = (_Float16)f1.y;
  h[4] = (_Float16)f0.z; h[5] = (_Float16)f1.z;
  h[6] = (_Float16)f0.w; h[7] = (_Float16)f1.w;
  return h;
}

// ============ prep: sort + x->fp16 only ============
__global__ void prep(const float* __restrict__ x, const int* __restrict__ indices,
                     _Float16* __restrict__ xh, int* __restrict__ inv,
                     int* __restrict__ meta)
{
  const int b = blockIdx.x;
  const int tid = threadIdx.x;

  if (b == 0) {  // ---- token sort into 128-aligned adapter groups ----
    __shared__ int cnt[4], cur[4];
    if (tid < 4) cnt[tid] = 0;
    __syncthreads();
    for (int t = tid; t < T_TOK; t += 256) atomicAdd(&cnt[indices[t]], 1);
    __syncthreads();
    if (tid == 0) {
      int off = 0;
      for (int a = 0; a < 4; ++a) {
        meta[a] = off;
        meta[5 + a] = off + cnt[a];
        cur[a] = off;
        off = (off + cnt[a] + 127) & ~127;
      }
      meta[4] = off;
    }
    __syncthreads();
    for (int i = tid; i < ROWS_PAD; i += 256) inv[i] = -1;
    __syncthreads();
    for (int t = tid; t < T_TOK; t += 256) {
      int a = indices[t];
      int p = atomicAdd(&cur[a], 1);
      inv[p] = t;
    }
    return;
  }

  // ---- x -> fp16, interleaved ----
  const int row = b - 1;          // 0..T_TOK (T_TOK = zero row)
  const int d0 = tid * 8;
  f16x8 h;
  if (row < T_TOK) {
    const float* src = x + (size_t)row * DIN + d0;
    h = cvt_interleave(*(const float4*)src, *(const float4*)(src + 4));
  } else {
#pragma unroll
    for (int j = 0; j < 8; ++j) h[j] = (_Float16)0.0f;
  }
  *(f16x8*)(xh + (size_t)row * DIN + d0) = h;
}

// ============ fused GEMM: in-loop dequant, 128x64 tile for 2x TLP ============
// EXACT R3-verified loop structure (single LDS buffer, 2 __syncthreads per
// K-step, compiler-scheduled waits, no inline asm / sched_barrier / setprio).
// Only change vs the measured 127us kernel: BN 128->64, doubling the grid to
// 1408 blocks (~4 blocks/CU resident vs ~2.75) so inter-wave TLP hides the
// per-K-step B-load latency chain that R3 exposed. Dequant math identical.
__global__ __launch_bounds__(256) void kfuse(
    const _Float16* __restrict__ xh, const float* __restrict__ wbf32,
    const int* __restrict__ qw0, const int* __restrict__ qw1,
    const int* __restrict__ qz0, const int* __restrict__ qz1,
    const float* __restrict__ sc0, const float* __restrict__ sc1,
    const float* __restrict__ bias,
    const int* __restrict__ inv, const int* __restrict__ meta,
    float* __restrict__ out)
{
  // XCD-bijective swizzle (1408 = 8*176): xcd = id&7 owns n-tiles
  // [xcd*16, xcd*16+16) across ALL m-tiles -> B slice L2-resident per XCD.
  const int id  = blockIdx.y * 128 + blockIdx.x;   // 0..1407
  const int xcd = id & 7;
  const int j   = id >> 3;                          // 0..175 (= 11m x 16n)
  const int m0  = (j >> 4) * BM;                    // 11 m-tiles
  const int n0  = ((xcd << 4) | (j & 15)) * BN;     // 128 n-tiles

  if (m0 >= meta[4]) return;
  int ad = 0;
  if (m0 >= meta[1]) ad = 1;
  if (m0 >= meta[2]) ad = 2;
  if (m0 >= meta[3]) ad = 3;
  if (m0 >= meta[5 + ad]) return;      // tile entirely pad

  const int sl = n0 >> 12;
  const int tid  = threadIdx.x;
  const int wave = tid >> 6;
  const int lane = tid & 63;
  const int quad = lane >> 4;
  const int l16  = lane & 15;
  const int wm = (wave & 1) << 6;      // 2 waves along M (64 rows each)
  const int wn = (wave >> 1) << 5;     // 2 waves along N (32 cols each)

  __shared__ __align__(16) char smem[12288];  // A [0,8K), B [8K,12K)

  f32x4 acc[4][2];
#pragma unroll
  for (int i = 0; i < 4; ++i)
#pragma unroll
    for (int jj = 0; jj < 2; ++jj) acc[i][jj] = (f32x4)0.0f;

  // A staging: staged chunk (tid&3) holds source chunk (tid&3)^((row>>1)&3)
  const int kch = (((tid & 3) ^ ((tid >> 3) & 3)) << 3);
  const int rloc = tid >> 2;
  int r0 = inv[m0 + rloc];       if (r0 < 0) r0 = T_TOK;   // pad -> zero row
  int r1 = inv[m0 + rloc + 64];  if (r1 < 0) r1 = T_TOK;
  const _Float16* ag0 = xh + (size_t)r0 * DIN + kch;
  const _Float16* ag1 = xh + (size_t)r1 * DIN + kch;
  char* sa0 = smem +        wave * 1024;
  char* sa1 = smem + 4096 + wave * 1024;

  // B dequant setup: thread -> row o_local (0..63), k-chunk kq (0..3)
  const int o_local = tid >> 2;
  const int kq = tid & 3;
  const int o = n0 + o_local;
  const int o_sl = o & (OSL - 1);
  const int* qwp = (sl ? qw1 : qw0) + ((size_t)ad * OSL + o_sl) * (DIN / 8) + kq;
  const int zw = (sl ? qz1 : qz0)[ad * (OSL / 8) + (o_sl >> 3)];
  const float s = (sl ? sc1 : sc0)[(size_t)ad * OSL + o_sl];
  const int z = (zw >> ((o_sl & 7) << 2)) & 0xF;
  f16x2 s2; s2[0] = s2[1] = (_Float16)s;
  f16x2 k2; k2[0] = k2[1] = (_Float16)(float)(-(1024 + z));
  const float* wbp = wbf32 + (size_t)o * DIN + (kq << 3);  // f32 base row

  const int bswz = (o_local >> 1) & 3;
  char* bw = smem + 8192 + o_local * 64 + ((kq ^ bswz) << 4);
  const int qoff = ((quad ^ ((l16 >> 1) & 3)) << 4);

  for (int k0 = 0; k0 < DIN; k0 += BK) {
    gload16(ag0, sa0);
    gload16(ag1, sa1);
    const uint32_t wx = (uint32_t)(*qwp);
    const float4 f0 = *(const float4*)(wbp);
    const float4 f1 = *(const float4*)(wbp + 4);
    union U { f16x8 v; f16x2 p[4]; } W_, h0;
    W_.v = cvt_interleave(f0, f1);     // this thread's 8 base-weight cols
#pragma unroll
    for (int jj = 0; jj < 4; ++jj) {
      uint32_t t0 = ((wx >> (4 * jj)) & 0x000F000Fu) | 0x64006400u;
      h0.p[jj] = (u2h(t0) + k2) * s2 + W_.p[jj];
    }
    *(f16x8*)bw = h0.v;
    __syncthreads();

    f16x8 af[4], bfr[2];
#pragma unroll
    for (int t = 0; t < 4; ++t)
      af[t] = *(const f16x8*)(smem + (wm + t * 16 + l16) * 64 + qoff);
#pragma unroll
    for (int t = 0; t < 2; ++t)
      bfr[t] = *(const f16x8*)(smem + 8192 + (wn + t * 16 + l16) * 64 + qoff);
#pragma unroll
    for (int mt = 0; mt < 4; ++mt)
#pragma unroll
      for (int nt = 0; nt < 2; ++nt)
        acc[mt][nt] = __builtin_amdgcn_mfma_f32_16x16x32_f16(af[mt], bfr[nt], acc[mt][nt], 0, 0, 0);
    __syncthreads();

    ag0 += BK; ag1 += BK; qwp += 4; wbp += BK;
  }

  // C/D: col=lane&15, row=quad*4+reg; scatter to out[token], +bias
#pragma unroll
  for (int mt = 0; mt < 4; ++mt) {
    const int rowb = m0 + wm + mt * 16 + quad * 4;
    int tk[4];
#pragma unroll
    for (int r = 0; r < 4; ++r) tk[r] = inv[rowb + r];
#pragma unroll
    for (int nt = 0; nt < 2; ++nt) {
      const int col = n0 + wn + nt * 16 + l16;
      const float bv = bias[col];
#pragma unroll
      for (int r = 0; r < 4; ++r) {
        if (tk[r] >= 0)
          out[(size_t)tk[r] * NOUT + col] = acc[mt][nt][r] + bv;
      }
    }
  }
}

extern "C" void kernel_launch(void* const* d_in, const int* in_sizes, int n_in,
                              void* d_out, int out_size, void* d_ws, size_t ws_size,
                              hipStream_t stream) {
  const float* x    = (const float*)d_in[0];
  const float* wb   = (const float*)d_in[1];
  const float* bias = (const float*)d_in[2];
  const int*   qw0  = (const int*)d_in[3];
  const int*   qw1  = (const int*)d_in[4];
  const int*   qz0  = (const int*)d_in[5];
  const int*   qz1  = (const int*)d_in[6];
  const float* sc0  = (const float*)d_in[7];
  const float* sc1  = (const float*)d_in[8];
  const int*   indices = (const int*)d_in[11];
  float* out = (float*)d_out;

  // workspace: xh [(T_TOK+1)*DIN f16] | inv | meta  (~4.3 MB total)
  char* w = (char*)d_ws;
  _Float16* xh = (_Float16*)w;
  size_t off = (size_t)(T_TOK + 1) * DIN * 2;
  int* inv  = (int*)(w + off);
  int* meta = inv + ROWS_PAD;

  prep<<<2 + T_TOK, 256, 0, stream>>>(x, indices, xh, inv, meta);
  kfuse<<<dim3(128, 11), 256, 0, stream>>>(xh, wb, qw0, qw1, qz0, qz1, sc0, sc1,
                                           bias, inv, meta, out);
}

// Round 8
// 241.119 us; speedup vs baseline: 1.1386x; 1.0191x over previous
//
#include <hip/hip_runtime.h>
#include <stdint.h>

// Problem constants
#define T_TOK 1024
#define DIN   2048
#define NOUT  8192   // 2*O
#define OSL   4096   // O per slice
#define ROWS_PAD 1408
#define BM 128
#define BN 128
#define BK 64       // two 32-k sub-tiles per barrier pair

typedef _Float16 f16x8 __attribute__((ext_vector_type(8)));
typedef _Float16 f16x2 __attribute__((ext_vector_type(2)));
typedef float    f32x4 __attribute__((ext_vector_type(4)));

__device__ __forceinline__ void gload16(const void* gp, void* lp) {
  __builtin_amdgcn_global_load_lds(
      (__attribute__((address_space(1))) void*)gp,
      (__attribute__((address_space(3))) void*)lp, 16, 0, 0);
}

__device__ __forceinline__ f16x2 u2h(uint32_t u) {
  union { uint32_t u; f16x2 h; } c; c.u = u; return c.h;
}

__device__ __forceinline__ f16x8 cvt_interleave(float4 f0, float4 f1) {
  // k-order [0,4,1,5,2,6,3,7] so packed-nibble pairs (n_j, n_{j+4}) line up
  f16x8 h;
  h[0] = (_Float16)f0.x; h[1] = (_Float16)f1.x;
  h[2] = (_Float16)f0.y; h[3] = (_Float16)f1.y;
  h[4] = (_Float16)f0.z; h[5] = (_Float16)f1.z;
  h[6] = (_Float16)f0.w; h[7] = (_Float16)f1.w;
  return h;
}

// ============ prep: sort + x->fp16 only ============
__global__ void prep(const float* __restrict__ x, const int* __restrict__ indices,
                     _Float16* __restrict__ xh, int* __restrict__ inv,
                     int* __restrict__ meta)
{
  const int b = blockIdx.x;
  const int tid = threadIdx.x;

  if (b == 0) {  // ---- token sort into 128-aligned adapter groups ----
    __shared__ int cnt[4], cur[4];
    if (tid < 4) cnt[tid] = 0;
    __syncthreads();
    for (int t = tid; t < T_TOK; t += 256) atomicAdd(&cnt[indices[t]], 1);
    __syncthreads();
    if (tid == 0) {
      int off = 0;
      for (int a = 0; a < 4; ++a) {
        meta[a] = off;
        meta[5 + a] = off + cnt[a];
        cur[a] = off;
        off = (off + cnt[a] + 127) & ~127;
      }
      meta[4] = off;
    }
    __syncthreads();
    for (int i = tid; i < ROWS_PAD; i += 256) inv[i] = -1;
    __syncthreads();
    for (int t = tid; t < T_TOK; t += 256) {
      int a = indices[t];
      int p = atomicAdd(&cur[a], 1);
      inv[p] = t;
    }
    return;
  }

  // ---- x -> fp16, interleaved ----
  const int row = b - 1;          // 0..T_TOK (T_TOK = zero row)
  const int d0 = tid * 8;
  f16x8 h;
  if (row < T_TOK) {
    const float* src = x + (size_t)row * DIN + d0;
    h = cvt_interleave(*(const float4*)src, *(const float4*)(src + 4));
  } else {
#pragma unroll
    for (int j = 0; j < 8; ++j) h[j] = (_Float16)0.0f;
  }
  *(f16x8*)(xh + (size_t)row * DIN + d0) = h;
}

// ============ fused GEMM: in-loop dequant, BK=64 (2 sub-tiles / barrier pair) ======
// R3-verified structure and mappings; the only change is step fattening:
// per iteration stage TWO 32-k sub-tiles of A (global_load_lds), load TWO
// sub-tiles of B-source into regs (int2 qw + 4x float4 wb each), dequant both,
// one __syncthreads, MFMA both sub-tiles, one __syncthreads. Halves the count
// of reg-load waits and barrier drains that R3/R7 showed to be the fixed cost.
__global__ __launch_bounds__(256) void kfuse(
    const _Float16* __restrict__ xh, const float* __restrict__ wbf32,
    const int* __restrict__ qw0, const int* __restrict__ qw1,
    const int* __restrict__ qz0, const int* __restrict__ qz1,
    const float* __restrict__ sc0, const float* __restrict__ sc1,
    const float* __restrict__ bias,
    const int* __restrict__ inv, const int* __restrict__ meta,
    float* __restrict__ out)
{
  // XCD-bijective swizzle (704 = 8*88): xcd = id%8 owns n-tiles [xcd*8, xcd*8+8)
  const int id = blockIdx.y * 64 + blockIdx.x;            // dispatch-linear, 0..703
  const int m0 = (id >> 6) * BM;
  const int n0 = (((id & 7) << 3) | ((id >> 3) & 7)) * BN;

  if (m0 >= meta[4]) return;
  int ad = 0;
  if (m0 >= meta[1]) ad = 1;
  if (m0 >= meta[2]) ad = 2;
  if (m0 >= meta[3]) ad = 3;
  if (m0 >= meta[5 + ad]) return;      // tile entirely pad

  const int sl = n0 >> 12;
  const int tid  = threadIdx.x;
  const int wave = tid >> 6;
  const int lane = tid & 63;
  const int quad = lane >> 4;
  const int l16  = lane & 15;
  const int wm = (wave & 1) << 6;
  const int wn = (wave >> 1) << 6;

  // LDS: A sub0 [0,8K), A sub1 [8K,16K), B sub0 [16K,24K), B sub1 [24K,32K)
  __shared__ __align__(16) char smem[32768];

  f32x4 acc[4][4];
#pragma unroll
  for (int i = 0; i < 4; ++i)
#pragma unroll
    for (int j = 0; j < 4; ++j) acc[i][j] = (f32x4)0.0f;

  // A staging: staged chunk (tid&3) holds source chunk (tid&3)^((row>>1)&3)
  const int kch = (((tid & 3) ^ ((tid >> 3) & 3)) << 3);
  const int rloc = tid >> 2;
  int r0 = inv[m0 + rloc];       if (r0 < 0) r0 = T_TOK;   // pad -> zero row
  int r1 = inv[m0 + rloc + 64];  if (r1 < 0) r1 = T_TOK;
  const _Float16* ag0 = xh + (size_t)r0 * DIN + kch;
  const _Float16* ag1 = xh + (size_t)r1 * DIN + kch;
  const int saoff0 = wave * 1024;          // rows 0..63 of sub-tile
  const int saoff1 = 4096 + wave * 1024;   // rows 64..127

  // B dequant setup: thread -> row o_local (0..127), k-half (tid&1) of each sub-tile
  const int o_local = tid >> 1;
  const int o = n0 + o_local;
  const int o_sl = o & (OSL - 1);
  const int* qwp = (sl ? qw1 : qw0) + ((size_t)ad * OSL + o_sl) * (DIN / 8) + ((tid & 1) << 1);
  const int zw = (sl ? qz1 : qz0)[ad * (OSL / 8) + (o_sl >> 3)];
  const float s = (sl ? sc1 : sc0)[(size_t)ad * OSL + o_sl];
  const int z = (zw >> ((o_sl & 7) << 2)) & 0xF;
  f16x2 s2; s2[0] = s2[1] = (_Float16)s;
  f16x2 k2; k2[0] = k2[1] = (_Float16)(float)(-(1024 + z));
  const float* wbp = wbf32 + (size_t)o * DIN + ((tid & 1) << 4);  // f32 base row

  const int bswz = (o_local >> 1) & 3;
  const int bwrel0 = o_local * 64 + (((((tid & 1) << 1)    ) ^ bswz) << 4);
  const int bwrel1 = o_local * 64 + (((((tid & 1) << 1) | 1) ^ bswz) << 4);
  const int qoff = ((quad ^ ((l16 >> 1) & 3)) << 4);

  for (int k0 = 0; k0 < DIN; k0 += BK) {
    // ---- stage A: both 32-k sub-tiles ----
    gload16(ag0,      smem +        saoff0);
    gload16(ag1,      smem +        saoff1);
    gload16(ag0 + 32, smem + 8192 + saoff0);
    gload16(ag1 + 32, smem + 8192 + saoff1);
    // ---- B-source register loads: both sub-tiles ----
    const int2 qv0 = *(const int2*)(qwp);
    const int2 qv1 = *(const int2*)(qwp + 4);
    float4 fa0 = *(const float4*)(wbp);
    float4 fa1 = *(const float4*)(wbp + 4);
    float4 fa2 = *(const float4*)(wbp + 8);
    float4 fa3 = *(const float4*)(wbp + 12);
    float4 fb0 = *(const float4*)(wbp + 32);
    float4 fb1 = *(const float4*)(wbp + 36);
    float4 fb2 = *(const float4*)(wbp + 40);
    float4 fb3 = *(const float4*)(wbp + 44);
    // ---- dequant sub-tile 0 -> B0 ----
    {
      union U { f16x8 v; f16x2 p[4]; } A_, B_, h0, h1;
      A_.v = cvt_interleave(fa0, fa1);
      B_.v = cvt_interleave(fa2, fa3);
      const uint32_t wx = (uint32_t)qv0.x, wy = (uint32_t)qv0.y;
#pragma unroll
      for (int j = 0; j < 4; ++j) {
        uint32_t t0 = ((wx >> (4 * j)) & 0x000F000Fu) | 0x64006400u;
        uint32_t t1 = ((wy >> (4 * j)) & 0x000F000Fu) | 0x64006400u;
        h0.p[j] = (u2h(t0) + k2) * s2 + A_.p[j];
        h1.p[j] = (u2h(t1) + k2) * s2 + B_.p[j];
      }
      *(f16x8*)(smem + 16384 + bwrel0) = h0.v;
      *(f16x8*)(smem + 16384 + bwrel1) = h1.v;
    }
    // ---- dequant sub-tile 1 -> B1 ----
    {
      union U { f16x8 v; f16x2 p[4]; } A_, B_, h0, h1;
      A_.v = cvt_interleave(fb0, fb1);
      B_.v = cvt_interleave(fb2, fb3);
      const uint32_t wx = (uint32_t)qv1.x, wy = (uint32_t)qv1.y;
#pragma unroll
      for (int j = 0; j < 4; ++j) {
        uint32_t t0 = ((wx >> (4 * j)) & 0x000F000Fu) | 0x64006400u;
        uint32_t t1 = ((wy >> (4 * j)) & 0x000F000Fu) | 0x64006400u;
        h0.p[j] = (u2h(t0) + k2) * s2 + A_.p[j];
        h1.p[j] = (u2h(t1) + k2) * s2 + B_.p[j];
      }
      *(f16x8*)(smem + 24576 + bwrel0) = h0.v;
      *(f16x8*)(smem + 24576 + bwrel1) = h1.v;
    }
    __syncthreads();   // drains A gloads + ds_writes (and reg loads already used)

    // ---- MFMA: sub-tile 0 then sub-tile 1 ----
#pragma unroll
    for (int sub = 0; sub < 2; ++sub) {
      f16x8 af[4], bfr[4];
#pragma unroll
      for (int t = 0; t < 4; ++t)
        af[t] = *(const f16x8*)(smem + sub * 8192 + (wm + t * 16 + l16) * 64 + qoff);
#pragma unroll
      for (int t = 0; t < 4; ++t)
        bfr[t] = *(const f16x8*)(smem + 16384 + sub * 8192 + (wn + t * 16 + l16) * 64 + qoff);
#pragma unroll
      for (int mt = 0; mt < 4; ++mt)
#pragma unroll
        for (int nt = 0; nt < 4; ++nt)
          acc[mt][nt] = __builtin_amdgcn_mfma_f32_16x16x32_f16(af[mt], bfr[nt], acc[mt][nt], 0, 0, 0);
    }
    __syncthreads();

    ag0 += BK; ag1 += BK; qwp += 8; wbp += BK;
  }

  // C/D: col=lane&15, row=quad*4+reg; scatter to out[token], +bias
#pragma unroll
  for (int mt = 0; mt < 4; ++mt) {
    const int rowb = m0 + wm + mt * 16 + quad * 4;
    int tk[4];
#pragma unroll
    for (int r = 0; r < 4; ++r) tk[r] = inv[rowb + r];
#pragma unroll
    for (int nt = 0; nt < 4; ++nt) {
      const int col = n0 + wn + nt * 16 + l16;
      const float bv = bias[col];
#pragma unroll
      for (int r = 0; r < 4; ++r) {
        if (tk[r] >= 0)
          out[(size_t)tk[r] * NOUT + col] = acc[mt][nt][r] + bv;
      }
    }
  }
}

extern "C" void kernel_launch(void* const* d_in, const int* in_sizes, int n_in,
                              void* d_out, int out_size, void* d_ws, size_t ws_size,
                              hipStream_t stream) {
  const float* x    = (const float*)d_in[0];
  const float* wb   = (const float*)d_in[1];
  const float* bias = (const float*)d_in[2];
  const int*   qw0  = (const int*)d_in[3];
  const int*   qw1  = (const int*)d_in[4];
  const int*   qz0  = (const int*)d_in[5];
  const int*   qz1  = (const int*)d_in[6];
  const float* sc0  = (const float*)d_in[7];
  const float* sc1  = (const float*)d_in[8];
  const int*   indices = (const int*)d_in[11];
  float* out = (float*)d_out;

  // workspace: xh [(T_TOK+1)*DIN f16] | inv | meta  (~4.3 MB total)
  char* w = (char*)d_ws;
  _Float16* xh = (_Float16*)w;
  size_t off = (size_t)(T_TOK + 1) * DIN * 2;
  int* inv  = (int*)(w + off);
  int* meta = inv + ROWS_PAD;

  prep<<<2 + T_TOK, 256, 0, stream>>>(x, indices, xh, inv, meta);
  kfuse<<<dim3(64, 11), 256, 0, stream>>>(xh, wb, qw0, qw1, qz0, qz1, sc0, sc1,
                                          bias, inv, meta, out);
}